// Round 8
// baseline (231.098 us; speedup 1.0000x reference)
//
#include <hip/hip_runtime.h>
#include <math.h>

#define COS_EPS 1e-8f

typedef float vfloat4 __attribute__((ext_vector_type(4)));

__device__ __forceinline__ float dot4(vfloat4 a, vfloat4 b) {
    return fmaf(a.x, b.x, fmaf(a.y, b.y, fmaf(a.z, b.z, a.w * b.w)));
}

// R8: thread-per-sample. Each thread privately accumulates dot, |e|^2,
// |p|^2 for ONE sample: the hot loop is pure load+FMA with ZERO cross-lane
// ops, so the compiler can keep an arbitrarily deep vmcnt window (no
// per-sample drain -- the serialization every previous round shared).
// Lane l walks row s+l in 64B line-sized steps (4 x float4 = one cache
// line per lane per stream per unrolled iter): every fetched line is fully
// consumed, same line traffic as coalesced layout. Cosine per thread; one
// butterfly + LDS + atomic at kernel end only.
__global__ __launch_bounds__(256) void assignment_loss_kernel(
    const float* __restrict__ emb,      // [B, D]
    const int*   __restrict__ labels,   // [B]
    const float* __restrict__ protos,   // [C, D]
    float*       __restrict__ acc,      // [1] pre-zeroed
    int B, int D)
{
    const int tid     = blockIdx.x * blockDim.x + threadIdx.x;
    const int nthread = gridDim.x * blockDim.x;
    const int lane    = threadIdx.x & 63;
    const int wib     = threadIdx.x >> 6;
    const int wpb     = blockDim.x >> 6;

    float local = 0.0f;

    if (D == 512) {
        for (int s = tid; s < B; s += nthread) {
            const int lbl = labels[s];                        // coalesced across lane
            const vfloat4* __restrict__ e = (const vfloat4*)(emb    + (size_t)s   * 512);
            const vfloat4* __restrict__ p = (const vfloat4*)(protos + (size_t)lbl * 512);

            float dot = 0.f, esq = 0.f, psq = 0.f;
            // 128 float4 chunks; unroll 8 -> 16 independent loads in flight
            // per thread per unrolled iter, no cross-lane dependency anywhere.
            #pragma unroll 8
            for (int c = 0; c < 128; ++c) {
                vfloat4 ev = e[c];
                vfloat4 pv = p[c];
                dot += dot4(ev, pv);
                esq += dot4(ev, ev);
                psq += dot4(pv, pv);
            }

            float en = fmaxf(sqrtf(esq), COS_EPS);            // torch eps semantics
            float pn = fmaxf(sqrtf(psq), COS_EPS);
            local += dot / (en * pn);
        }
    } else {
        const int nchunks = D >> 2;                           // float4 per row
        for (int s = tid; s < B; s += nthread) {
            const int lbl = labels[s];
            const vfloat4* e = (const vfloat4*)(emb    + (size_t)s   * (size_t)D);
            const vfloat4* p = (const vfloat4*)(protos + (size_t)lbl * (size_t)D);
            float dot = 0.f, esq = 0.f, psq = 0.f;
            for (int c = 0; c < nchunks; ++c) {
                vfloat4 ev = e[c];
                vfloat4 pv = p[c];
                dot += dot4(ev, pv);
                esq += dot4(ev, ev);
                psq += dot4(pv, pv);
            }
            float en = fmaxf(sqrtf(esq), COS_EPS);
            float pn = fmaxf(sqrtf(psq), COS_EPS);
            local += dot / (en * pn);
        }
    }

    // one reduction for the whole kernel: 64-lane butterfly -> LDS -> atomic
    #pragma unroll
    for (int off = 32; off > 0; off >>= 1) local += __shfl_xor(local, off, 64);

    __shared__ float smem[8];
    if (lane == 0) smem[wib] = local;
    __syncthreads();
    if (threadIdx.x == 0) {
        float bs = 0.0f;
        for (int w = 0; w < wpb; ++w) bs += smem[w];
        atomicAdd(acc, bs);
    }
}

__global__ void assignment_loss_finalize(const float* __restrict__ acc,
                                         float* __restrict__ out,
                                         float invB)
{
    out[0] = 1.0f - acc[0] * invB;
}

extern "C" void kernel_launch(void* const* d_in, const int* in_sizes, int n_in,
                              void* d_out, int out_size, void* d_ws, size_t ws_size,
                              hipStream_t stream) {
    const float* emb    = (const float*)d_in[0];   // [B, D] float32
    const int*   labels = (const int*)  d_in[1];   // [B]
    const float* protos = (const float*)d_in[2];   // [C, D] float32
    float*       out    = (float*)d_out;           // scalar float32
    float*       acc    = (float*)d_ws;

    const int B = in_sizes[1];
    const int D = in_sizes[0] / B;                 // 512

    hipMemsetAsync(acc, 0, sizeof(float), stream); // d_ws poisoned 0xAA each call

    const int block = 256;
    // one thread per sample, 2 samples/thread: 512 waves/XCD spread,
    // 128 blocks -> generous MLP per thread carries the BW (occupancy
    // proven non-binding in R6).
    const int grid  = 512;                          // 131072 threads? no: B/256/2... see below
    // grid*block = 131072 threads -> each handles <=1 sample when B=65536?
    // grid-stride loop handles any ratio; 512*256=131072 > B so one sample
    // per thread for the first 65536 threads, rest idle-reduce. Use 256
    // blocks to give every thread exactly one sample instead:
    assignment_loss_kernel<<<256, block, 0, stream>>>(emb, labels, protos, acc, B, D);
    assignment_loss_finalize<<<1, 1, 0, stream>>>(acc, out, 1.0f / (float)B);
}